// Round 1
// baseline (429.670 us; speedup 1.0000x reference)
//
#include <hip/hip_runtime.h>
#include <math.h>

#define N_NODES 7
#define HDIM 128
#define F_IN 32
#define LN_EPS 1e-5f
#define ALPHA 0.2f
#define NEG_CONST -9e15f

__global__ __launch_bounds__(256) void gat_fused(
    const float* __restrict__ x, const float* __restrict__ adj,
    const float* __restrict__ Wp, const float* __restrict__ bp,
    const float* __restrict__ W1, const float* __restrict__ a1,
    const float* __restrict__ g1, const float* __restrict__ b1,
    const float* __restrict__ W2, const float* __restrict__ a2,
    const float* __restrict__ g2, const float* __restrict__ b2,
    float* __restrict__ out, int BT)
{
    __shared__ float x_s[F_IN];
    __shared__ float h_s[N_NODES][HDIM];
    __shared__ float wh_s[N_NODES][HDIM];
    __shared__ float hp_s[N_NODES][HDIM];
    __shared__ float f_src[N_NODES], f_dst[N_NODES];
    __shared__ float att_s[N_NODES][N_NODES];

    const int t = blockIdx.x;
    const int tid = threadIdx.x;
    const float scale = 0.08838834764831845f;  // 128^-0.5

    if (t >= BT) return;

    // ---- load x row (32 floats) ----
    if (tid < F_IN) x_s[tid] = x[(size_t)t * F_IN + tid];
    __syncthreads();

    // ---- projection: h = x @ Wp + bp ; output cols = N*H = 896 ----
    {
        const int k = tid & (HDIM - 1);
        const int nb = (tid >> 7) * 4;          // 0 or 4
        float acc[4] = {0.f, 0.f, 0.f, 0.f};
        for (int f = 0; f < F_IN; ++f) {
            const float xv = x_s[f];
            const float* row = Wp + (size_t)f * (N_NODES * HDIM);
            #pragma unroll
            for (int i = 0; i < 4; ++i) {
                const int n = nb + i;
                const int nc = (n < N_NODES) ? n : (N_NODES - 1);  // clamp, store guarded
                acc[i] += xv * row[nc * HDIM + k];
            }
        }
        #pragma unroll
        for (int i = 0; i < 4; ++i) {
            const int n = nb + i;
            if (n < N_NODES) h_s[n][k] = acc[i] + bp[n * HDIM + k];
        }
    }
    __syncthreads();

    const float* Ws[2] = {W1, W2};
    const float* as[2] = {a1, a2};
    const float* gs[2] = {g1, g2};
    const float* bs[2] = {b1, b2};

    for (int l = 0; l < 2; ++l) {
        const float* __restrict__ W = Ws[l];
        const float* __restrict__ a = as[l];
        const float* __restrict__ g = gs[l];
        const float* __restrict__ b = bs[l];

        // ---- Wh = h @ W : 896 outputs, dot over 128 ----
        {
            const int k = tid & (HDIM - 1);
            const int nb = (tid >> 7) * 4;
            float acc[4] = {0.f, 0.f, 0.f, 0.f};
            for (int j = 0; j < HDIM; ++j) {
                const float w = W[(size_t)j * HDIM + k];
                #pragma unroll
                for (int i = 0; i < 4; ++i) {
                    const int n = nb + i;
                    const int nc = (n < N_NODES) ? n : (N_NODES - 1);
                    acc[i] += h_s[nc][j] * w;
                }
            }
            #pragma unroll
            for (int i = 0; i < 4; ++i) {
                const int n = nb + i;
                if (n < N_NODES) wh_s[n][k] = acc[i];
            }
        }
        __syncthreads();

        // ---- f_src[n] = Wh[n] . a[:H] ; f_dst[n] = Wh[n] . a[H:] ----
        {
            const int grp = tid >> 5;   // 0..7
            const int lane = tid & 31;
            if (grp < N_NODES) {
                float s1 = 0.f, s2 = 0.f;
                #pragma unroll
                for (int q = 0; q < 4; ++q) {
                    const int k = lane * 4 + q;
                    const float v = wh_s[grp][k];
                    s1 += v * a[k];
                    s2 += v * a[HDIM + k];
                }
                for (int off = 16; off > 0; off >>= 1) {
                    s1 += __shfl_down(s1, off, 32);
                    s2 += __shfl_down(s2, off, 32);
                }
                if (lane == 0) { f_src[grp] = s1; f_dst[grp] = s2; }
            }
        }
        __syncthreads();

        // ---- attention rows: e_ij = lrelu(f_src_i + f_dst_j)*scale, mask, softmax_j ----
        if (tid < N_NODES) {
            const int i = tid;
            float e[N_NODES];
            float m = -INFINITY;
            #pragma unroll
            for (int j = 0; j < N_NODES; ++j) {
                float v = f_src[i] + f_dst[j];
                v = (v > 0.f ? v : ALPHA * v) * scale;
                if (!(adj[i * N_NODES + j] > 0.f)) v = NEG_CONST;
                e[j] = v;
                m = fmaxf(m, v);
            }
            float s = 0.f;
            #pragma unroll
            for (int j = 0; j < N_NODES; ++j) {
                const float p = expf(e[j] - m);
                att_s[i][j] = p;
                s += p;
            }
            const float inv = 1.f / s;
            #pragma unroll
            for (int j = 0; j < N_NODES; ++j) att_s[i][j] *= inv;
        }
        __syncthreads();

        // ---- h_prime = att @ Wh ----
        {
            const int k = tid & (HDIM - 1);
            const int nb = (tid >> 7) * 4;
            #pragma unroll
            for (int i = 0; i < 4; ++i) {
                const int n = nb + i;
                const int nc = (n < N_NODES) ? n : (N_NODES - 1);
                float acc = 0.f;
                #pragma unroll
                for (int j = 0; j < N_NODES; ++j)
                    acc += att_s[nc][j] * wh_s[j][k];
                if (n < N_NODES) hp_s[n][k] = acc;
            }
        }
        __syncthreads();

        // ---- layernorm + residual: h = LN(hp)*g + b + h ----
        {
            const int grp = tid >> 5;
            const int lane = tid & 31;
            if (grp < N_NODES) {
                float v[4];
                float s = 0.f, ss = 0.f;
                #pragma unroll
                for (int q = 0; q < 4; ++q) {
                    v[q] = hp_s[grp][lane * 4 + q];
                    s += v[q];
                    ss += v[q] * v[q];
                }
                for (int off = 16; off > 0; off >>= 1) {
                    s  += __shfl_down(s, off, 32);
                    ss += __shfl_down(ss, off, 32);
                }
                s  = __shfl(s, 0, 32);
                ss = __shfl(ss, 0, 32);
                const float m = s * (1.f / HDIM);
                const float var = ss * (1.f / HDIM) - m * m;
                const float rinv = rsqrtf(var + LN_EPS);
                #pragma unroll
                for (int q = 0; q < 4; ++q) {
                    const int k = lane * 4 + q;
                    h_s[grp][k] = (v[q] - m) * rinv * g[k] + b[k] + h_s[grp][k];
                }
            }
        }
        __syncthreads();
    }

    // ---- out = mean over nodes ----
    if (tid < HDIM) {
        float s = 0.f;
        #pragma unroll
        for (int n = 0; n < N_NODES; ++n) s += h_s[n][tid];
        out[(size_t)t * HDIM + tid] = s * (1.f / N_NODES);
    }
}

extern "C" void kernel_launch(void* const* d_in, const int* in_sizes, int n_in,
                              void* d_out, int out_size, void* d_ws, size_t ws_size,
                              hipStream_t stream) {
    const float* x   = (const float*)d_in[0];
    const float* adj = (const float*)d_in[1];
    const float* Wp  = (const float*)d_in[2];
    const float* bp  = (const float*)d_in[3];
    const float* W1  = (const float*)d_in[4];
    const float* a1  = (const float*)d_in[5];
    const float* g1  = (const float*)d_in[6];
    const float* b1  = (const float*)d_in[7];
    const float* W2  = (const float*)d_in[8];
    const float* a2  = (const float*)d_in[9];
    const float* g2  = (const float*)d_in[10];
    const float* b2  = (const float*)d_in[11];
    const int BT = in_sizes[0] / F_IN;

    gat_fused<<<dim3(BT), dim3(256), 0, stream>>>(
        x, adj, Wp, bp, W1, a1, g1, b1, W2, a2, g2, b2, (float*)d_out, BT);
}

// Round 2
// 141.861 us; speedup vs baseline: 3.0288x; 3.0288x over previous
//
#include <hip/hip_runtime.h>
#include <math.h>
#include <stdint.h>

#define NN 7
#define HD 128
#define FIN 32
#define TPB 8
#define RWS (TPB * NN)   // 56 rows per block
#define LN_EPS 1e-5f
#define ALPHA 0.2f
#define NEG_CONST -9e15f
#define SCALE 0.08838834764831845f  // 128^-0.5

typedef __bf16 bf16x8 __attribute__((ext_vector_type(8)));
typedef float  f32x4  __attribute__((ext_vector_type(4)));

__device__ __forceinline__ uint16_t f2bf_u(float f) {
    union { float f; uint32_t u; } v; v.f = f;
    uint32_t r = v.u + 0x7FFFu + ((v.u >> 16) & 1u);  // RNE
    return (uint16_t)(r >> 16);
}

__global__ __launch_bounds__(256, 2) void gat_fused(
    const float* __restrict__ x, const float* __restrict__ adj,
    const float* __restrict__ Wp, const float* __restrict__ bp,
    const float* __restrict__ W1, const float* __restrict__ a1,
    const float* __restrict__ g1, const float* __restrict__ b1,
    const float* __restrict__ W2, const float* __restrict__ a2,
    const float* __restrict__ g2, const float* __restrict__ b2,
    float* __restrict__ out, int BT)
{
    // residual stream h: fp32 (precision anchor). GEMM operands bf16.
    __shared__ __align__(16) float    h_s[RWS][132];   // 29568 B
    __shared__ __align__(16) uint16_t g_s[64][136];    // 17408 B (att@h, bf16, M-padded)
    __shared__ __align__(16) uint16_t w_s[5120];       // 10240 B (union: proj [128][40] / layer [32][136])
    __shared__ __align__(16) uint16_t x_s[16][40];     //  1280 B
    __shared__ float att_s[TPB][7][8];                 //  1792 B
    __shared__ float fsrc_s[RWS], fdst_s[RWS];         //   448 B
    __shared__ __align__(16) float va_s[HD], vb_s[HD]; //  1024 B
    __shared__ float a_s[2 * HD];                      //  1024 B
    __shared__ __align__(16) float gl_s[HD], bl_s[HD]; //  1024 B
    // total 63808 B -> 2 blocks/CU

    const int tid  = threadIdx.x;
    const int lane = tid & 63;
    const int wave = tid >> 6;
    const int t0   = blockIdx.x * TPB;

    // MFMA lane geometry (16x16x32): A[row=lane&15][k=(lane>>4)*8 + i]
    const int frow = lane & 15;
    const int kgrp = lane >> 4;
    const int kb   = kgrp * 8;

    // ---- stage x -> bf16 (pad token rows 8..15 with zero); zero g pad rows ----
    {
        int t = tid >> 5, f = tid & 31;
        float v = (t0 + t < BT) ? x[(size_t)(t0 + t) * FIN + f] : 0.f;
        x_s[t][f]     = f2bf_u(v);
        x_s[8 + t][f] = 0;
    }
    for (int idx = tid; idx < 8 * 136; idx += 256)
        (&g_s[0][0])[RWS * 136 + idx] = 0;
    __syncthreads();

    bf16x8 ax = *reinterpret_cast<const bf16x8*>(&x_s[frow][kb]);  // A = x (M=16 tokens, K=32)

    // ---- projection: h = x @ Wp + bp, via MFMA, one 128-col chunk per node ----
    for (int nc = 0; nc < NN; ++nc) {
        {   // stage Wp chunk transposed bf16: w_s[c*40 + f], c=0..127, f=0..31
            int c  = tid & 127;
            int fb = (tid >> 7) * 16;
            #pragma unroll
            for (int p = 0; p < 8; ++p) {
                int f = fb + p * 2;
                float w0 = Wp[(size_t)f       * (NN * HD) + nc * HD + c];
                float w1 = Wp[(size_t)(f + 1) * (NN * HD) + nc * HD + c];
                uint32_t u = (uint32_t)f2bf_u(w0) | ((uint32_t)f2bf_u(w1) << 16);
                *reinterpret_cast<uint32_t*>(&w_s[c * 40 + f]) = u;
            }
        }
        __syncthreads();
        #pragma unroll
        for (int ntl = 0; ntl < 2; ++ntl) {
            int kk = (wave * 2 + ntl) * 16 + frow;  // col within this node's 128
            bf16x8 bv = *reinterpret_cast<const bf16x8*>(&w_s[kk * 40 + kb]);
            f32x4 acc = {0.f, 0.f, 0.f, 0.f};
            acc = __builtin_amdgcn_mfma_f32_16x16x32_bf16(ax, bv, acc, 0, 0, 0);
            float bias = bp[nc * HD + kk];
            #pragma unroll
            for (int r = 0; r < 4; ++r) {
                int t = kgrp * 4 + r;               // C row = token
                if (t < TPB) h_s[t * NN + nc][kk] = acc[r] + bias;
            }
        }
        __syncthreads();
    }

    const float* Wl[2]  = {W1, W2};
    const float* al[2]  = {a1, a2};
    const float* gll[2] = {g1, g2};
    const float* bll[2] = {b1, b2};

    for (int l = 0; l < 2; ++l) {
        const float* __restrict__ W = Wl[l];

        // preload a (256), gamma/beta (128)
        a_s[tid] = al[l][tid];
        if (tid < HD) { gl_s[tid] = gll[l][tid]; bl_s[tid] = bll[l][tid]; }
        __syncthreads();

        // va[j] = sum_o W[j][o]*a[o],  vb[j] = sum_o W[j][o]*a[H+o]
        {
            int j = tid & 127, which = tid >> 7;
            const float* rowp = W + (size_t)j * HD;
            const float* av   = a_s + which * HD;
            float acc = 0.f;
            #pragma unroll 8
            for (int o = 0; o < HD; o += 4) {
                f32x4 wv = *reinterpret_cast<const f32x4*>(&rowp[o]);
                acc += wv[0]*av[o] + wv[1]*av[o+1] + wv[2]*av[o+2] + wv[3]*av[o+3];
            }
            (which ? vb_s : va_s)[j] = acc;
        }
        __syncthreads();

        // f_src[r] = h[r].va, f_dst[r] = h[r].vb   (4 threads per row)
        if (tid < 4 * RWS) {
            int r     = tid >> 2;
            int which = (tid >> 1) & 1;
            int half  = tid & 1;
            const float* vv = which ? vb_s : va_s;
            int base = half * 64;
            float acc = 0.f;
            #pragma unroll 4
            for (int c = 0; c < 64; c += 4) {
                f32x4 hv  = *reinterpret_cast<const f32x4*>(&h_s[r][base + c]);
                f32x4 vv4 = *reinterpret_cast<const f32x4*>(&vv[base + c]);
                acc += hv[0]*vv4[0] + hv[1]*vv4[1] + hv[2]*vv4[2] + hv[3]*vv4[3];
            }
            acc += __shfl_xor(acc, 1, 64);
            if (half == 0) (which ? fdst_s : fsrc_s)[r] = acc;
        }
        __syncthreads();

        // attention softmax rows (7x7 per token)
        if (tid < 64) {
            int t = tid >> 3, i = tid & 7;
            if (i < NN) {
                float fs = fsrc_s[t * NN + i];
                float e[NN];
                float m = -INFINITY;
                #pragma unroll
                for (int jn = 0; jn < NN; ++jn) {
                    float v = fs + fdst_s[t * NN + jn];
                    v = (v > 0.f ? v : ALPHA * v) * SCALE;
                    v = (adj[i * NN + jn] > 0.f) ? v : NEG_CONST;
                    e[jn] = v;
                    m = fmaxf(m, v);
                }
                float ssum = 0.f;
                #pragma unroll
                for (int jn = 0; jn < NN; ++jn) { e[jn] = __expf(e[jn] - m); ssum += e[jn]; }
                float inv = 1.f / ssum;
                #pragma unroll
                for (int jn = 0; jn < NN; ++jn) att_s[t][i][jn] = e[jn] * inv;
            }
        }
        __syncthreads();

        // g = att @ h  (fp32 math, bf16 store; A-operand of the layer GEMM)
        {
            int t = tid >> 5, c4 = (tid & 31) * 4;
            f32x4 hrow[NN];
            #pragma unroll
            for (int jn = 0; jn < NN; ++jn)
                hrow[jn] = *reinterpret_cast<const f32x4*>(&h_s[t * NN + jn][c4]);
            #pragma unroll
            for (int n = 0; n < NN; ++n) {
                f32x4 o = {0.f, 0.f, 0.f, 0.f};
                #pragma unroll
                for (int jn = 0; jn < NN; ++jn) {
                    float av = att_s[t][n][jn];
                    o[0] += av * hrow[jn][0];
                    o[1] += av * hrow[jn][1];
                    o[2] += av * hrow[jn][2];
                    o[3] += av * hrow[jn][3];
                }
                uint32_t u0 = (uint32_t)f2bf_u(o[0]) | ((uint32_t)f2bf_u(o[1]) << 16);
                uint32_t u1 = (uint32_t)f2bf_u(o[2]) | ((uint32_t)f2bf_u(o[3]) << 16);
                *reinterpret_cast<uint32_t*>(&g_s[t * NN + n][c4])     = u0;
                *reinterpret_cast<uint32_t*>(&g_s[t * NN + n][c4 + 2]) = u1;
            }
        }
        __syncthreads();

        // GEMM: hp = g @ W  (h_prime = (att@h)@W). C stays in registers.
        f32x4 Cacc[8];
        #pragma unroll
        for (int q = 0; q < 8; ++q) Cacc[q] = (f32x4){0.f, 0.f, 0.f, 0.f};
        bf16x8 av4[4];
        #pragma unroll
        for (int ks = 0; ks < 4; ++ks)
            av4[ks] = *reinterpret_cast<const bf16x8*>(&g_s[wave * 16 + frow][ks * 32 + kb]);

        for (int ncc = 0; ncc < 4; ++ncc) {
            {   // stage W chunk transposed bf16: w_s[c*136 + j], c=0..31 (cols ncc*32+c), j=0..127
                int c  = tid & 31;
                int jb = (tid >> 5) * 2;
                #pragma unroll
                for (int p = 0; p < 8; ++p) {
                    int j = jb + p * 16;
                    float w0 = W[(size_t)j       * HD + ncc * 32 + c];
                    float w1 = W[(size_t)(j + 1) * HD + ncc * 32 + c];
                    uint32_t u = (uint32_t)f2bf_u(w0) | ((uint32_t)f2bf_u(w1) << 16);
                    *reinterpret_cast<uint32_t*>(&w_s[c * 136 + j]) = u;
                }
            }
            __syncthreads();
            #pragma unroll
            for (int ntl = 0; ntl < 2; ++ntl) {
                int cl = ntl * 16 + frow;
                f32x4 acc = Cacc[ncc * 2 + ntl];
                #pragma unroll
                for (int ks = 0; ks < 4; ++ks) {
                    bf16x8 bv = *reinterpret_cast<const bf16x8*>(&w_s[cl * 136 + ks * 32 + kb]);
                    acc = __builtin_amdgcn_mfma_f32_16x16x32_bf16(av4[ks], bv, acc, 0, 0, 0);
                }
                Cacc[ncc * 2 + ntl] = acc;
            }
            __syncthreads();
        }

        // LayerNorm + residual, fully in registers (reduce across the 16 frow-lanes)
        {
            float mean4[4], rinv4[4];
            #pragma unroll
            for (int r = 0; r < 4; ++r) {
                float s = 0.f, sq = 0.f;
                #pragma unroll
                for (int q = 0; q < 8; ++q) { float c = Cacc[q][r]; s += c; sq += c * c; }
                #pragma unroll
                for (int msk = 1; msk <= 8; msk <<= 1) {
                    s  += __shfl_xor(s,  msk, 64);
                    sq += __shfl_xor(sq, msk, 64);
                }
                float mean = s * (1.f / HD);
                float var  = sq * (1.f / HD) - mean * mean;
                mean4[r] = mean;
                rinv4[r] = rsqrtf(var + LN_EPS);
            }
            #pragma unroll
            for (int q = 0; q < 8; ++q) {
                int col = q * 16 + frow;
                float gv = gl_s[col], bv = bl_s[col];
                #pragma unroll
                for (int r = 0; r < 4; ++r) {
                    int m = wave * 16 + kgrp * 4 + r;
                    if (m < RWS)
                        h_s[m][col] += (Cacc[q][r] - mean4[r]) * rinv4[r] * gv + bv;
                }
            }
        }
        __syncthreads();
    }

    // ---- out = mean over nodes ----
    {
        int t = tid >> 5, c4 = (tid & 31) * 4;
        if (t0 + t < BT) {
            f32x4 s = {0.f, 0.f, 0.f, 0.f};
            #pragma unroll
            for (int n = 0; n < NN; ++n) {
                f32x4 hv = *reinterpret_cast<const f32x4*>(&h_s[t * NN + n][c4]);
                s[0] += hv[0]; s[1] += hv[1]; s[2] += hv[2]; s[3] += hv[3];
            }
            const float inv7 = 1.f / 7.f;
            f32x4 o = {s[0] * inv7, s[1] * inv7, s[2] * inv7, s[3] * inv7};
            *reinterpret_cast<f32x4*>(&out[(size_t)(t0 + t) * HD + c4]) = o;
        }
    }
}

extern "C" void kernel_launch(void* const* d_in, const int* in_sizes, int n_in,
                              void* d_out, int out_size, void* d_ws, size_t ws_size,
                              hipStream_t stream) {
    const float* x   = (const float*)d_in[0];
    const float* adj = (const float*)d_in[1];
    const float* Wp  = (const float*)d_in[2];
    const float* bp  = (const float*)d_in[3];
    const float* W1  = (const float*)d_in[4];
    const float* a1  = (const float*)d_in[5];
    const float* g1  = (const float*)d_in[6];
    const float* b1  = (const float*)d_in[7];
    const float* W2  = (const float*)d_in[8];
    const float* a2  = (const float*)d_in[9];
    const float* g2  = (const float*)d_in[10];
    const float* b2  = (const float*)d_in[11];
    const int BT = in_sizes[0] / FIN;
    const int blocks = (BT + TPB - 1) / TPB;

    gat_fused<<<dim3(blocks), dim3(256), 0, stream>>>(
        x, adj, Wp, bp, W1, a1, g1, b1, W2, a2, g2, b2, (float*)d_out, BT);
}

// Round 3
// 131.823 us; speedup vs baseline: 3.2595x; 1.0762x over previous
//
#include <hip/hip_runtime.h>
#include <math.h>
#include <stdint.h>

#define NN 7
#define HD 128
#define FIN 32
#define TPB 8
#define RWS (TPB * NN)   // 56 rows per block
#define LN_EPS 1e-5f
#define ALPHA 0.2f
#define NEG_CONST -9e15f
#define SCALE 0.08838834764831845f  // 128^-0.5

typedef __bf16 bf16x8 __attribute__((ext_vector_type(8)));
typedef float  f32x4  __attribute__((ext_vector_type(4)));

__device__ __forceinline__ uint16_t f2bf_u(float f) {
    union { float f; uint32_t u; } v; v.f = f;
    uint32_t r = v.u + 0x7FFFu + ((v.u >> 16) & 1u);  // RNE
    return (uint16_t)(r >> 16);
}

// ws layout (bytes): WpT[7*128][32] bf16 @0 (57344) | W1T[128][128] bf16 @57344
// | W2T[128][128] bf16 @90112 | vab[4][128] f32 @122880 (2048)
#define WS_W1T  57344
#define WS_W2T  90112
#define WS_VAB  122880

__global__ __launch_bounds__(256) void prep_weights(
    const float* __restrict__ Wp,
    const float* __restrict__ W1, const float* __restrict__ a1,
    const float* __restrict__ W2, const float* __restrict__ a2,
    uint16_t* __restrict__ WpT, uint16_t* __restrict__ W1T,
    uint16_t* __restrict__ W2T, float* __restrict__ vab)
{
    const int bid = blockIdx.x, tid = threadIdx.x;
    if (bid < 112) {                 // WpT[gc][f] = Wp[f][gc], 28672 elems
        int idx = bid * 256 + tid;
        int gc = idx >> 5, f = idx & 31;
        WpT[idx] = f2bf_u(Wp[(size_t)f * (NN * HD) + gc]);
    } else if (bid < 176) {          // W1T[c][k] = W1[k][c]
        int idx = (bid - 112) * 256 + tid;
        int c = idx >> 7, k = idx & 127;
        W1T[idx] = f2bf_u(W1[(size_t)k * HD + c]);
    } else if (bid < 240) {          // W2T[c][k] = W2[k][c]
        int idx = (bid - 176) * 256 + tid;
        int c = idx >> 7, k = idx & 127;
        W2T[idx] = f2bf_u(W2[(size_t)k * HD + c]);
    } else {                         // vab[l][which][j] = sum_o W[j][o]*a[which*128+o]
        for (int d = tid; d < 512; d += 256) {
            int l = d >> 8, which = (d >> 7) & 1, j = d & 127;
            const float* W = l ? W2 : W1;
            const float* a = (l ? a2 : a1) + which * HD;
            const float* row = W + (size_t)j * HD;
            float acc = 0.f;
            #pragma unroll 8
            for (int o = 0; o < HD; o += 4) {
                f32x4 wv = *reinterpret_cast<const f32x4*>(&row[o]);
                acc += wv[0]*a[o] + wv[1]*a[o+1] + wv[2]*a[o+2] + wv[3]*a[o+3];
            }
            vab[d] = acc;
        }
    }
}

__global__ __launch_bounds__(256, 3) void gat_fused(
    const float* __restrict__ x, const float* __restrict__ adj,
    const float* __restrict__ bp,
    const uint16_t* __restrict__ WpT, const uint16_t* __restrict__ W1T,
    const uint16_t* __restrict__ W2T, const float* __restrict__ vab,
    const float* __restrict__ g1, const float* __restrict__ b1,
    const float* __restrict__ g2, const float* __restrict__ b2,
    float* __restrict__ out, int BT)
{
    __shared__ __align__(16) float    h_s[RWS][132];   // 29568 B  (fp32 residual stream)
    __shared__ __align__(16) uint16_t g_s[64][136];    // 17408 B  (att@h in bf16, M-padded)
    __shared__ __align__(16) uint16_t x_s[16][40];     //  1280 B
    __shared__ float att_s[TPB][7][8];                 //  1792 B
    __shared__ float fsrc_s[RWS], fdst_s[RWS];         //   448 B
    // total 50496 B -> 3 blocks/CU

    const int tid  = threadIdx.x;
    const int lane = tid & 63;
    const int wave = tid >> 6;
    const int t0   = blockIdx.x * TPB;

    const int frow = lane & 15;      // A row / B col within fragment
    const int kgrp = lane >> 4;      // k-group
    const int kb   = kgrp * 8;

    // ---- stage x -> bf16 (pad token rows 8..15 zero); zero g_s pad rows ----
    {
        int t = tid >> 5, f = tid & 31;
        float v = (t0 + t < BT) ? x[(size_t)(t0 + t) * FIN + f] : 0.f;
        x_s[t][f]     = f2bf_u(v);
        x_s[8 + t][f] = 0;
    }
    for (int idx = tid; idx < 8 * 136; idx += 256)
        (&g_s[0][0])[RWS * 136 + idx] = 0;
    __syncthreads();

    bf16x8 ax = *reinterpret_cast<const bf16x8*>(&x_s[frow][kb]);

    // ---- projection: h = x @ Wp + bp. B-frags straight from global (L2-hot). ----
    #pragma unroll
    for (int i = 0; i < 14; ++i) {
        const int ct  = wave * 14 + i;          // 56 col-tiles of 16
        const int gc0 = ct * 16;
        bf16x8 bv = *reinterpret_cast<const bf16x8*>(WpT + (size_t)(gc0 + frow) * FIN + kb);
        f32x4 acc = {0.f, 0.f, 0.f, 0.f};
        acc = __builtin_amdgcn_mfma_f32_16x16x32_bf16(ax, bv, acc, 0, 0, 0);
        const int nc = gc0 >> 7;
        const int kk = (gc0 & 127) + frow;
        const float bias = bp[gc0 + frow];
        #pragma unroll
        for (int r = 0; r < 4; ++r) {
            int t = kgrp * 4 + r;
            if (t < TPB) h_s[t * NN + nc][kk] = acc[r] + bias;
        }
    }
    __syncthreads();

    const float* gl[2] = {g1, g2};
    const float* bl[2] = {b1, b2};

    for (int l = 0; l < 2; ++l) {
        const uint16_t* __restrict__ WT = l ? W2T : W1T;
        const float* __restrict__ va = vab + l * 256;
        const float* __restrict__ vb = va + HD;

        // ---- f_src[r] = h[r].va ; f_dst[r] = h[r].vb  (4 threads per row) ----
        if (tid < 4 * RWS) {
            int r     = tid >> 2;
            int which = (tid >> 1) & 1;
            int half  = tid & 1;
            const float* vv = which ? vb : va;
            int base = half * 64;
            float acc = 0.f;
            #pragma unroll 4
            for (int c = 0; c < 64; c += 4) {
                f32x4 hv  = *reinterpret_cast<const f32x4*>(&h_s[r][base + c]);
                f32x4 vv4 = *reinterpret_cast<const f32x4*>(&vv[base + c]);
                acc += hv[0]*vv4[0] + hv[1]*vv4[1] + hv[2]*vv4[2] + hv[3]*vv4[3];
            }
            acc += __shfl_xor(acc, 1, 64);
            if (half == 0) (which ? fdst_s : fsrc_s)[r] = acc;
        }
        __syncthreads();

        // ---- 7x7 softmax per token ----
        if (tid < 64) {
            int t = tid >> 3, i = tid & 7;
            if (i < NN) {
                float fs = fsrc_s[t * NN + i];
                float e[NN];
                float m = -INFINITY;
                #pragma unroll
                for (int jn = 0; jn < NN; ++jn) {
                    float v = fs + fdst_s[t * NN + jn];
                    v = (v > 0.f ? v : ALPHA * v) * SCALE;
                    v = (adj[i * NN + jn] > 0.f) ? v : NEG_CONST;
                    e[jn] = v;
                    m = fmaxf(m, v);
                }
                float ssum = 0.f;
                #pragma unroll
                for (int jn = 0; jn < NN; ++jn) { e[jn] = __expf(e[jn] - m); ssum += e[jn]; }
                float inv = 1.f / ssum;
                #pragma unroll
                for (int jn = 0; jn < NN; ++jn) att_s[t][i][jn] = e[jn] * inv;
            }
        }
        __syncthreads();

        // ---- g = att @ h (fp32 math, bf16 store) ----
        {
            int t = tid >> 5, c4 = (tid & 31) * 4;
            f32x4 hrow[NN];
            #pragma unroll
            for (int jn = 0; jn < NN; ++jn)
                hrow[jn] = *reinterpret_cast<const f32x4*>(&h_s[t * NN + jn][c4]);
            #pragma unroll
            for (int n = 0; n < NN; ++n) {
                f32x4 o = {0.f, 0.f, 0.f, 0.f};
                #pragma unroll
                for (int jn = 0; jn < NN; ++jn) {
                    float av = att_s[t][n][jn];
                    o[0] += av * hrow[jn][0];
                    o[1] += av * hrow[jn][1];
                    o[2] += av * hrow[jn][2];
                    o[3] += av * hrow[jn][3];
                }
                uint32_t u0 = (uint32_t)f2bf_u(o[0]) | ((uint32_t)f2bf_u(o[1]) << 16);
                uint32_t u1 = (uint32_t)f2bf_u(o[2]) | ((uint32_t)f2bf_u(o[3]) << 16);
                *reinterpret_cast<uint32_t*>(&g_s[t * NN + n][c4])     = u0;
                *reinterpret_cast<uint32_t*>(&g_s[t * NN + n][c4 + 2]) = u1;
            }
        }
        __syncthreads();

        // ---- GEMM: hp = g @ W ; B-frags from global, A from LDS, C in regs ----
        f32x4 Cacc[8];
        bf16x8 av4[4];
        #pragma unroll
        for (int ks = 0; ks < 4; ++ks)
            av4[ks] = *reinterpret_cast<const bf16x8*>(&g_s[wave * 16 + frow][ks * 32 + kb]);
        #pragma unroll
        for (int ntl = 0; ntl < 8; ++ntl) {
            const uint16_t* bp_g = WT + (size_t)(ntl * 16 + frow) * HD + kb;
            f32x4 acc = {0.f, 0.f, 0.f, 0.f};
            #pragma unroll
            for (int ks = 0; ks < 4; ++ks) {
                bf16x8 bv = *reinterpret_cast<const bf16x8*>(bp_g + ks * 32);
                acc = __builtin_amdgcn_mfma_f32_16x16x32_bf16(av4[ks], bv, acc, 0, 0, 0);
            }
            Cacc[ntl] = acc;
        }

        // ---- LayerNorm + residual in registers (reduce across 16 frow-lanes) ----
        {
            const float* gg = gl[l];
            const float* bb = bl[l];
            float mean4[4], rinv4[4];
            #pragma unroll
            for (int r = 0; r < 4; ++r) {
                float s = 0.f, sq = 0.f;
                #pragma unroll
                for (int q = 0; q < 8; ++q) { float c = Cacc[q][r]; s += c; sq += c * c; }
                #pragma unroll
                for (int msk = 1; msk <= 8; msk <<= 1) {
                    s  += __shfl_xor(s,  msk, 64);
                    sq += __shfl_xor(sq, msk, 64);
                }
                float mean = s * (1.f / HD);
                float var  = sq * (1.f / HD) - mean * mean;
                mean4[r] = mean;
                rinv4[r] = rsqrtf(var + LN_EPS);
            }
            #pragma unroll
            for (int q = 0; q < 8; ++q) {
                int col = q * 16 + frow;
                float gv = gg[col], bv = bb[col];
                #pragma unroll
                for (int r = 0; r < 4; ++r) {
                    int m = wave * 16 + kgrp * 4 + r;
                    if (m < RWS)
                        h_s[m][col] += (Cacc[q][r] - mean4[r]) * rinv4[r] * gv + bv;
                }
            }
        }
        __syncthreads();
    }

    // ---- out = mean over nodes ----
    {
        int t = tid >> 5, c4 = (tid & 31) * 4;
        if (t0 + t < BT) {
            f32x4 s = {0.f, 0.f, 0.f, 0.f};
            #pragma unroll
            for (int n = 0; n < NN; ++n) {
                f32x4 hv = *reinterpret_cast<const f32x4*>(&h_s[t * NN + n][c4]);
                s[0] += hv[0]; s[1] += hv[1]; s[2] += hv[2]; s[3] += hv[3];
            }
            const float inv7 = 1.f / 7.f;
            f32x4 o = {s[0] * inv7, s[1] * inv7, s[2] * inv7, s[3] * inv7};
            *reinterpret_cast<f32x4*>(&out[(size_t)(t0 + t) * HD + c4]) = o;
        }
    }
}

extern "C" void kernel_launch(void* const* d_in, const int* in_sizes, int n_in,
                              void* d_out, int out_size, void* d_ws, size_t ws_size,
                              hipStream_t stream) {
    const float* x   = (const float*)d_in[0];
    const float* adj = (const float*)d_in[1];
    const float* Wp  = (const float*)d_in[2];
    const float* bp  = (const float*)d_in[3];
    const float* W1  = (const float*)d_in[4];
    const float* a1  = (const float*)d_in[5];
    const float* g1  = (const float*)d_in[6];
    const float* b1  = (const float*)d_in[7];
    const float* W2  = (const float*)d_in[8];
    const float* a2  = (const float*)d_in[9];
    const float* g2  = (const float*)d_in[10];
    const float* b2  = (const float*)d_in[11];
    const int BT = in_sizes[0] / FIN;
    const int blocks = (BT + TPB - 1) / TPB;

    uint8_t* ws = (uint8_t*)d_ws;
    uint16_t* WpT = (uint16_t*)(ws);
    uint16_t* W1T = (uint16_t*)(ws + WS_W1T);
    uint16_t* W2T = (uint16_t*)(ws + WS_W2T);
    float*    vab = (float*)   (ws + WS_VAB);

    prep_weights<<<dim3(241), dim3(256), 0, stream>>>(Wp, W1, a1, W2, a2,
                                                      WpT, W1T, W2T, vab);
    gat_fused<<<dim3(blocks), dim3(256), 0, stream>>>(
        x, adj, bp, WpT, W1T, W2T, vab, g1, b1, g2, b2, (float*)d_out, BT);
}